// Round 6
// baseline (578.594 us; speedup 1.0000x reference)
//
#include <hip/hip_runtime.h>
#include <math.h>

// Problem constants (Physics_Attention_Irregular_Mesh)
#define BQ   4
#define NTOK 16384
#define DIMM 256
#define HH   8
#define DDIM 64
#define SSL  64
#define INNERD 512
#define BN_TOK (BQ*NTOK)   // 65536

typedef __attribute__((ext_vector_type(8))) short short8;   // 8 bf16 (4 VGPRs)
typedef __attribute__((ext_vector_type(4))) float f32x4;    // 4 fp32 acc

// bf16 <-> f32 helpers (RNE)
__device__ inline float bf2f(unsigned short u) {
    union { float f; unsigned int i; } v; v.i = ((unsigned int)u) << 16; return v.f;
}
__device__ inline unsigned short f2bf(float f) {
    union { float f; unsigned int i; } v; v.f = f;
    unsigned int r = v.i + 0x7FFFu + ((v.i >> 16) & 1u);
    return (unsigned short)(r >> 16);
}

// async global->LDS, 16 B per lane (wave-uniform LDS base + lane*16)
__device__ __forceinline__ void gl_lds16(const void* g, void* l) {
    __builtin_amdgcn_global_load_lds(
        (const __attribute__((address_space(1))) unsigned int*)g,
        (__attribute__((address_space(3))) unsigned int*)l, 16, 0, 0);
}

// ---------------------------------------------------------------------------
// K0: merged logits weights (bf16): Wlogb[h*64+s] = Wslice[s] @ Wx_h,
//     blog = Wslice@bx_h + bslice.  (fx weights no longer needed merged.)
// ---------------------------------------------------------------------------
__global__ void k_prep(const float* __restrict__ Wx, const float* __restrict__ bx,
                       const float* __restrict__ Wslice, const float* __restrict__ bslice,
                       unsigned short* __restrict__ Wlogb, float* __restrict__ blog)
{
    int row = blockIdx.x;   // 0..511
    int t = threadIdx.x;    // 64
    int h = row >> 6, s = row & 63;
    for (int c = t; c < 256; c += 64) {
        float acc = 0.f;
        for (int d = 0; d < 64; ++d)
            acc += Wslice[s*64 + d] * Wx[(h*64 + d)*256 + c];
        Wlogb[row*256 + c] = f2bf(acc);
    }
    if (t == 0) {
        float acc = bslice[s];
        for (int d = 0; d < 64; ++d) acc += Wslice[s*64 + d] * bx[h*64 + d];
        blog[row] = acc;
    }
}

// ---------------------------------------------------------------------------
// K0b: x (fp32) -> xb (bf16 token-major) AND xbT (bf16 c-major) via LDS tile.
// One block = 64 tokens. Xs padded to 260 (column reads 2-way = free).
// ---------------------------------------------------------------------------
__global__ __launch_bounds__(256) void k_xcast2(
    const float* __restrict__ x, unsigned short* __restrict__ xb,
    unsigned short* __restrict__ xbT)
{
    __shared__ unsigned short Xs[64*260];
    int tb = blockIdx.x;         // 0..1023
    int tid = threadIdx.x;
    const float* src = x + (size_t)tb*64*256;
#pragma unroll
    for (int i = 0; i < 16; i++) {
        int f4 = i*256 + tid;            // 0..4095 float4s
        int tok = f4 >> 6, c4 = (f4 & 63)*4;
        float4 v = *(const float4*)(src + (size_t)f4*4);
        Xs[tok*260 + c4+0] = f2bf(v.x);
        Xs[tok*260 + c4+1] = f2bf(v.y);
        Xs[tok*260 + c4+2] = f2bf(v.z);
        Xs[tok*260 + c4+3] = f2bf(v.w);
    }
    __syncthreads();
    // token-major xb
    unsigned short* dxb = xb + (size_t)tb*64*256;
#pragma unroll
    for (int i = 0; i < 16; i++) {
        int u4 = i*256 + tid;            // ushort4 index
        int tok = u4 >> 6, c4 = (u4 & 63)*4;
        *(ushort4*)(dxb + tok*256 + c4) = *(const ushort4*)&Xs[tok*260 + c4];
    }
    // c-major xbT: thread tid = c, writes 64 tokens of its row
    int b = (tb*64) >> 14;
    int n0 = (tb*64) & (NTOK-1);
    unsigned short* dxT = xbT + ((size_t)(b*256 + tid))*NTOK + n0;
#pragma unroll
    for (int i = 0; i < 16; i++) {
        int t4 = i*4;
        ushort4 v = make_ushort4(Xs[(t4+0)*260 + tid], Xs[(t4+1)*260 + tid],
                                 Xs[(t4+2)*260 + tid], Xs[(t4+3)*260 + tid]);
        *(ushort4*)(dxT + t4) = v;
    }
}

// ---------------------------------------------------------------------------
// K1: logits GEMM C[65536 x 512] = xb @ Wlogb^T + blog, fused temp-scale +
// per-head softmax -> wbuf[token][h*64+s], fused norm (fp32 column sums via
// shuffle-reduce + atomicAdd). 128x128 tile, 2048 blocks, XCD swizzle.
// ---------------------------------------------------------------------------
__global__ __launch_bounds__(256) void k_gemm1(
    const unsigned short* __restrict__ Xb, const unsigned short* __restrict__ Wb,
    const float* __restrict__ bias, const float* __restrict__ temperature,
    unsigned short* __restrict__ wbuf, float* __restrict__ norm_acc)
{
    __shared__ unsigned short As[128*32];
    __shared__ unsigned short Bs[128*32];
    int bid = blockIdx.x;             // 2048
    int xcd = bid & 7;
    int inner = bid >> 3;             // 0..255
    int rt = xcd*64 + (inner >> 2);   // 0..511
    int ct = inner & 3;               // 0..3
    int m0 = rt*128, n0 = ct*128;
    int tid = threadIdx.x;
    int lane = tid & 63, w = tid >> 6;
    int wr = w >> 1, wc = w & 1;
    int lr = lane & 15, lq = lane >> 4;

    f32x4 acc[4][4];
#pragma unroll
    for (int i = 0; i < 4; i++)
#pragma unroll
        for (int j = 0; j < 4; j++) acc[i][j] = (f32x4)(0.f);

    int r0 = tid >> 2, kq0 = (tid & 3) * 8;

    for (int k0 = 0; k0 < 256; k0 += 32) {
        __syncthreads();
        gl_lds16(Xb + (size_t)(m0 + r0)*256 + k0 + kq0,      &As[(size_t)tid*8]);
        gl_lds16(Xb + (size_t)(m0 + 64 + r0)*256 + k0 + kq0, &As[(size_t)(tid+256)*8]);
        gl_lds16(Wb + (size_t)(n0 + r0)*256 + k0 + kq0,      &Bs[(size_t)tid*8]);
        gl_lds16(Wb + (size_t)(n0 + 64 + r0)*256 + k0 + kq0, &Bs[(size_t)(tid+256)*8]);
        __syncthreads();
        short8 af[4], bf[4];
#pragma unroll
        for (int i = 0; i < 4; i++) {
            af[i] = *(const short8*)&As[(wr*64 + i*16 + lr)*32 + lq*8];
            bf[i] = *(const short8*)&Bs[(wc*64 + i*16 + lr)*32 + lq*8];
        }
#pragma unroll
        for (int i = 0; i < 4; i++)
#pragma unroll
            for (int j = 0; j < 4; j++)
                acc[i][j] = __builtin_amdgcn_mfma_f32_16x16x32_bf16(af[i], bf[j], acc[i][j], 0, 0, 0);
    }

    int h = (n0 + wc*64) >> 6;        // ct*2 + wc
    int batch = m0 >> 14;
    float it = 1.f / fmaxf(temperature[h], 1e-4f);
    float bv[4];
#pragma unroll
    for (int j = 0; j < 4; j++) bv[j] = bias[n0 + wc*64 + j*16 + lr];
    float pn[4] = {0.f, 0.f, 0.f, 0.f};

#pragma unroll
    for (int i = 0; i < 4; i++) {
        int tokbase = m0 + wr*64 + i*16 + lq*4;
#pragma unroll
        for (int r = 0; r < 4; r++) {
            float v[4];
#pragma unroll
            for (int j = 0; j < 4; j++) v[j] = (acc[i][j][r] + bv[j]) * it;
            float mx = fmaxf(fmaxf(v[0], v[1]), fmaxf(v[2], v[3]));
            mx = fmaxf(mx, __shfl_xor(mx, 1));
            mx = fmaxf(mx, __shfl_xor(mx, 2));
            mx = fmaxf(mx, __shfl_xor(mx, 4));
            mx = fmaxf(mx, __shfl_xor(mx, 8));
            float e[4], sm = 0.f;
#pragma unroll
            for (int j = 0; j < 4; j++) { e[j] = __expf(v[j] - mx); sm += e[j]; }
            sm += __shfl_xor(sm, 1);
            sm += __shfl_xor(sm, 2);
            sm += __shfl_xor(sm, 4);
            sm += __shfl_xor(sm, 8);
            float inv = 1.f / sm;
            size_t rowoff = (size_t)(tokbase + r)*512 + n0 + wc*64 + lr;
#pragma unroll
            for (int j = 0; j < 4; j++) {
                float wv = e[j] * inv;
                pn[j] += wv;
                wbuf[rowoff + j*16] = f2bf(wv);
            }
        }
    }
    // norm: reduce over lq (lanes 16/32 apart), atomic per column
#pragma unroll
    for (int j = 0; j < 4; j++) {
        pn[j] += __shfl_xor(pn[j], 16);
        pn[j] += __shfl_xor(pn[j], 32);
    }
    if (lane < 16) {
#pragma unroll
        for (int j = 0; j < 4; j++)
            atomicAdd(&norm_acc[(batch*8 + h)*64 + j*16 + lr], pn[j]);
    }
}

// ---------------------------------------------------------------------------
// K2: Y[b,h,s,c] = sum_n w[b,n,h,s] * xb[b,n,c]   (MFMA, K=tokens)
// A = w^T (in-LDS transpose from wbuf), B = xbT rows (gl_lds16).
// grid (8 chunks x 32 bh); 2048 tokens per block; atomicAdd partials.
// ---------------------------------------------------------------------------
__global__ __launch_bounds__(256) void k_tokY(
    const unsigned short* __restrict__ wbuf, const unsigned short* __restrict__ xbT,
    float* __restrict__ Y)
{
    __shared__ unsigned short As[64*32];    // [s][n]
    __shared__ unsigned short Bs[256*32];   // [c][n]
    int chunk = blockIdx.x;   // 0..7
    int bh = blockIdx.y;      // 0..31
    int b = bh >> 3, h = bh & 7;
    int tid = threadIdx.x;
    int lane = tid & 63, w = tid >> 6;
    int lr = lane & 15, lq = lane >> 4;

    f32x4 acc[4][4];          // [i = s-frag][j = c-frag within wave's 64]
#pragma unroll
    for (int i = 0; i < 4; i++)
#pragma unroll
        for (int j = 0; j < 4; j++) acc[i][j] = (f32x4)(0.f);

    int tk = tid >> 3, s8 = (tid & 7)*8;
    int crow = tid >> 2, nn = (tid & 3)*8;
    size_t wrowbase = ((size_t)(b*NTOK + chunk*2048))*512 + h*64 + s8;
    const unsigned short* xTb = xbT + (size_t)b*256*NTOK + chunk*2048;

    for (int kk = 0; kk < 2048; kk += 32) {
        __syncthreads();
#pragma unroll
        for (int q = 0; q < 4; q++)
            gl_lds16(xTb + (size_t)(q*64 + crow)*NTOK + kk + nn,
                     &Bs[q*2048 + (size_t)tid*8]);
        short8 g = *(const short8*)(wbuf + wrowbase + (size_t)(kk + tk)*512);
#pragma unroll
        for (int j = 0; j < 8; j++)
            As[(s8 + j)*32 + tk] = ((unsigned short*)&g)[j];
        __syncthreads();
        short8 af[4], bfr[4];
#pragma unroll
        for (int i = 0; i < 4; i++)
            af[i] = *(const short8*)&As[(i*16 + lr)*32 + lq*8];
#pragma unroll
        for (int j = 0; j < 4; j++)
            bfr[j] = *(const short8*)&Bs[(w*64 + j*16 + lr)*32 + lq*8];
#pragma unroll
        for (int i = 0; i < 4; i++)
#pragma unroll
            for (int j = 0; j < 4; j++)
                acc[i][j] = __builtin_amdgcn_mfma_f32_16x16x32_bf16(af[i], bfr[j], acc[i][j], 0, 0, 0);
    }

#pragma unroll
    for (int i = 0; i < 4; i++)
#pragma unroll
        for (int j = 0; j < 4; j++) {
            int c = w*64 + j*16 + lr;
#pragma unroll
            for (int r = 0; r < 4; r++) {
                int s = i*16 + lq*4 + r;
                atomicAdd(&Y[((size_t)bh*64 + s)*256 + c], acc[i][j][r]);
            }
        }
}

// ---------------------------------------------------------------------------
// K2b: tok[bh][s][d] = (Y[bh][s]·Wfx[h*64+d] + norm*bfx[h*64+d]) / (norm+1e-5)
// ---------------------------------------------------------------------------
__global__ __launch_bounds__(256) void k_tokfin(
    const float* __restrict__ Y, const float* __restrict__ norm_,
    const float* __restrict__ Wfx, const float* __restrict__ bfx,
    float* __restrict__ tok)
{
    int bh = blockIdx.x; int h = bh & 7;
    int tid = threadIdx.x;
    for (int idx = tid; idx < 4096; idx += 256) {
        int d = idx >> 6, s = idx & 63;     // d uniform per 64-lane group
        const float* yr = Y + ((size_t)bh*64 + s)*256;
        const float* wr = Wfx + (size_t)(h*64 + d)*256;
        float a = 0.f;
        for (int c = 0; c < 256; ++c) a += yr[c] * wr[c];
        float nv = norm_[bh*64 + s];
        tok[(size_t)bh*4096 + s*64 + d] = (a + nv*bfx[h*64 + d]) / (nv + 1e-5f);
    }
}

// K3b: per b: kv = mean_h tok; kn = rownorm(kv@Wk^T); v = kv@Wv^T
__global__ __launch_bounds__(256) void k_kv(
    const float* __restrict__ tok, const float* __restrict__ Wk, const float* __restrict__ Wv,
    float* __restrict__ kn_out, float* __restrict__ v_out)
{
    __shared__ float KV[64][65];
    __shared__ float TMP[64][65];
    __shared__ float rn[64];
    int b = blockIdx.x, tid = threadIdx.x;
    for (int idx = tid; idx < 4096; idx += 256) {
        float s = 0.f;
        for (int h = 0; h < 8; ++h) s += tok[((size_t)(b*8 + h))*4096 + idx];
        KV[idx >> 6][idx & 63] = s * 0.125f;
    }
    __syncthreads();
    for (int idx = tid; idx < 4096; idx += 256) {
        int s = idx >> 6, d = idx & 63;
        float a = 0.f;
        for (int e = 0; e < 64; ++e) a += KV[s][e] * Wk[d*64 + e];
        TMP[s][d] = a;
    }
    __syncthreads();
    if (tid < 64) {
        float a = 0.f;
        for (int d = 0; d < 64; ++d) { float x = TMP[tid][d]; a += x*x; }
        rn[tid] = fmaxf(sqrtf(a), 1e-12f);
    }
    __syncthreads();
    for (int idx = tid; idx < 4096; idx += 256) {
        int s = idx >> 6, d = idx & 63;
        kn_out[(size_t)b*4096 + idx] = TMP[s][d] / rn[s];
    }
    for (int idx = tid; idx < 4096; idx += 256) {
        int s = idx >> 6, d = idx & 63;
        float a = 0.f;
        for (int e = 0; e < 64; ++e) a += KV[s][e] * Wv[d*64 + e];
        v_out[(size_t)b*4096 + idx] = a;
    }
}

// K3c: per (b,h): q = tok@Wq^T, cosine attn vs kn, softmax, @v, + srs*tok
__global__ __launch_bounds__(256) void k_attn(
    const float* __restrict__ tok, const float* __restrict__ Wq,
    const float* __restrict__ kn, const float* __restrict__ vbuf,
    const float* __restrict__ attn_scale, const float* __restrict__ srs,
    float* __restrict__ out_tok)
{
    __shared__ float Q[64][65];
    __shared__ float KN[64][65];
    __shared__ float L[64][65];
    __shared__ float rn[64];
    int h = blockIdx.x & 7, b = blockIdx.x >> 3;
    int bh = b*8 + h;
    int tid = threadIdx.x;
    for (int idx = tid; idx < 4096; idx += 256)
        KN[idx >> 6][idx & 63] = kn[(size_t)b*4096 + idx];
    __syncthreads();
    for (int idx = tid; idx < 4096; idx += 256) {
        int g = idx >> 6, d = idx & 63;
        float a = 0.f;
        for (int e = 0; e < 64; ++e) a += tok[(size_t)bh*4096 + g*64 + e] * Wq[d*64 + e];
        Q[g][d] = a;
    }
    __syncthreads();
    if (tid < 64) {
        float a = 0.f;
        for (int d = 0; d < 64; ++d) { float x = Q[tid][d]; a += x*x; }
        rn[tid] = fmaxf(sqrtf(a), 1e-12f);
    }
    __syncthreads();
    float scale = attn_scale[h];
    for (int idx = tid; idx < 4096; idx += 256) {
        int g = idx >> 6, s = idx & 63;
        float a = 0.f;
        for (int e = 0; e < 64; ++e) a += Q[g][e] * KN[s][e];
        L[g][s] = a / rn[g] * scale;
    }
    __syncthreads();
    if (tid < 64) {
        float mx = -1e30f;
        for (int s = 0; s < 64; ++s) mx = fmaxf(mx, L[tid][s]);
        float sm = 0.f;
        for (int s = 0; s < 64; ++s) { float e = expf(L[tid][s]-mx); L[tid][s] = e; sm += e; }
        float ivv = 1.f/sm;
        for (int s = 0; s < 64; ++s) L[tid][s] *= ivv;
    }
    __syncthreads();
    float srsv = srs[0];
    for (int idx = tid; idx < 4096; idx += 256) {
        int g = idx >> 6, d = idx & 63;
        float a = 0.f;
        for (int s = 0; s < 64; ++s) a += L[g][s] * vbuf[(size_t)b*4096 + s*64 + d];
        out_tok[(size_t)bh*4096 + idx] = a + srsv * tok[(size_t)bh*4096 + idx];
    }
}

// K3d: MTb[b][j][h*64+s] = sum_d out_tok[b,h,s,d] * Wout[j, h*64+d]  (bf16 out)
__global__ __launch_bounds__(256) void k_mt(
    const float* __restrict__ out_tok, const float* __restrict__ Wout,
    unsigned short* __restrict__ MTb)
{
    __shared__ float Wt[64][68];   // [d][j]
    __shared__ float Ot[64][68];   // [d][s]
    int jt = blockIdx.x, h = blockIdx.y, b = blockIdx.z;
    int j0 = jt * 64;
    int tid = threadIdx.x;
    int tx = tid & 15, ty = tid >> 4;
#pragma unroll
    for (int i = 0; i < 4; i++) {
        int flat = tid + i*256;
        int r = flat >> 4;
        int c4 = (flat & 15) * 4;
        float4 wv = *(const float4*)(Wout + (size_t)(j0+r)*512 + h*64 + c4);
        Wt[c4+0][r]=wv.x; Wt[c4+1][r]=wv.y; Wt[c4+2][r]=wv.z; Wt[c4+3][r]=wv.w;
        float4 ov = *(const float4*)(out_tok + ((size_t)(b*8+h)*64 + r)*64 + c4);
        Ot[c4+0][r]=ov.x; Ot[c4+1][r]=ov.y; Ot[c4+2][r]=ov.z; Ot[c4+3][r]=ov.w;
    }
    __syncthreads();
    float acc[4][4] = {{0.f}};
#pragma unroll 8
    for (int d = 0; d < 64; ++d) {
        float av[4], bv[4];
        *(float4*)av = *(const float4*)&Wt[d][ty*4];
        *(float4*)bv = *(const float4*)&Ot[d][tx*4];
#pragma unroll
        for (int i = 0; i < 4; i++)
#pragma unroll
            for (int j = 0; j < 4; j++) acc[i][j] += av[i]*bv[j];
    }
#pragma unroll
    for (int i = 0; i < 4; i++) {
        int j = j0 + ty*4 + i;
#pragma unroll
        for (int jj = 0; jj < 4; jj++) {
            int s = tx*4 + jj;
            MTb[((size_t)(b*256) + j)*512 + h*64 + s] = f2bf(acc[i][jj]);
        }
    }
}

// ---------------------------------------------------------------------------
// K5: MFMA GEMM. out[65536 x 256] = wbuf(bf16) @ MTb[b]^T + bout (fp32 out)
// ---------------------------------------------------------------------------
__global__ __launch_bounds__(256) void k_gemm2(
    const unsigned short* __restrict__ A, const unsigned short* __restrict__ Ball,
    const float* __restrict__ bias, float* __restrict__ C)
{
    __shared__ unsigned short As[128*32];
    __shared__ unsigned short Bs[128*32];
    int bid = blockIdx.x;             // 1024
    int xcd = bid & 7;
    int inner = bid >> 3;             // 0..127
    int rt = xcd*64 + (inner >> 1);   // 0..511
    int ct = inner & 1;
    int m0 = rt*128, n0 = ct*128;
    const unsigned short* Bm = Ball + (size_t)(m0 >> 14) * 256 * 512;
    int tid = threadIdx.x;
    int lane = tid & 63, w = tid >> 6;
    int wr = w >> 1, wc = w & 1;
    int lr = lane & 15, lq = lane >> 4;

    f32x4 acc[4][4];
#pragma unroll
    for (int i = 0; i < 4; i++)
#pragma unroll
        for (int j = 0; j < 4; j++) acc[i][j] = (f32x4)(0.f);

    int r0 = tid >> 2, kq0 = (tid & 3) * 8;

    for (int k0 = 0; k0 < 512; k0 += 32) {
        __syncthreads();
        gl_lds16(A + (size_t)(m0 + r0)*512 + k0 + kq0,       &As[(size_t)tid*8]);
        gl_lds16(A + (size_t)(m0 + 64 + r0)*512 + k0 + kq0,  &As[(size_t)(tid+256)*8]);
        gl_lds16(Bm + (size_t)(n0 + r0)*512 + k0 + kq0,      &Bs[(size_t)tid*8]);
        gl_lds16(Bm + (size_t)(n0 + 64 + r0)*512 + k0 + kq0, &Bs[(size_t)(tid+256)*8]);
        __syncthreads();
        short8 af[4], bf[4];
#pragma unroll
        for (int i = 0; i < 4; i++) {
            af[i] = *(const short8*)&As[(wr*64 + i*16 + lr)*32 + lq*8];
            bf[i] = *(const short8*)&Bs[(wc*64 + i*16 + lr)*32 + lq*8];
        }
#pragma unroll
        for (int i = 0; i < 4; i++)
#pragma unroll
            for (int j = 0; j < 4; j++)
                acc[i][j] = __builtin_amdgcn_mfma_f32_16x16x32_bf16(af[i], bf[j], acc[i][j], 0, 0, 0);
    }

#pragma unroll
    for (int j = 0; j < 4; j++) {
        int n = n0 + wc*64 + j*16 + lr;
        float bv = bias[n];
#pragma unroll
        for (int i = 0; i < 4; i++) {
            int mrow = m0 + wr*64 + i*16 + lq*4;
#pragma unroll
            for (int r = 0; r < 4; r++)
                C[(size_t)(mrow + r)*256 + n] = acc[i][j][r] + bv;
        }
    }
}

// ---------------------------------------------------------------------------
extern "C" void kernel_launch(void* const* d_in, const int* in_sizes, int n_in,
                              void* d_out, int out_size, void* d_ws, size_t ws_size,
                              hipStream_t stream)
{
    const float* x      = (const float*)d_in[0];
    const float* Wx     = (const float*)d_in[1];
    const float* bx     = (const float*)d_in[2];
    const float* Wfx    = (const float*)d_in[3];
    const float* bfx    = (const float*)d_in[4];
    const float* Wslice = (const float*)d_in[5];
    const float* bslice = (const float*)d_in[6];
    const float* temperature = (const float*)d_in[7];
    const float* Wq     = (const float*)d_in[8];
    const float* Wk     = (const float*)d_in[9];
    const float* Wv     = (const float*)d_in[10];
    const float* attn_scale = (const float*)d_in[11];
    const float* srs    = (const float*)d_in[12];
    const float* Wout   = (const float*)d_in[13];
    const float* bout   = (const float*)d_in[14];
    float* out = (float*)d_out;
    float* ws  = (float*)d_ws;

    // workspace layout (float offsets) — total ~71.7 MiB
    float* Y    = ws + 0;          // 4*8*64*256 = 524288
    float* norm = ws + 524288;     // 2048
    float* blog = ws + 526336;     // 1024 (512 used)
    float* kn   = ws + 527360;     // 16384
    float* vb   = ws + 543744;     // 16384
    float* ot   = ws + 560128;     // 131072
    float* tok  = ws + 691200;     // 131072
    unsigned short* Wlogb = (unsigned short*)(ws + 822272);  // 512*256   -> 65536 floats
    unsigned short* MTb   = (unsigned short*)(ws + 887808);  // 4*256*512 -> 262144 floats
    unsigned short* xb    = (unsigned short*)(ws + 1149952); // 65536*256 -> 8388608 floats
    unsigned short* xbT   = (unsigned short*)(ws + 9538560); // 65536*256 -> 8388608 floats

    hipMemsetAsync(Y, 0, (524288 + 2048) * sizeof(float), stream);  // Y + norm
    k_prep<<<512, 64, 0, stream>>>(Wx, bx, Wslice, bslice, Wlogb, blog);
    k_xcast2<<<1024, 256, 0, stream>>>(x, xb, xbT);
    k_gemm1<<<2048, 256, 0, stream>>>(xb, Wlogb, blog, temperature, (unsigned short*)(ws + 9538560 + 8388608), norm);
    // NOTE: wbuf lives after xbT
    {
        unsigned short* wbuf = (unsigned short*)(ws + 9538560 + 8388608); // 65536*512 bf16
        k_tokY<<<dim3(8, 32), 256, 0, stream>>>(wbuf, xbT, Y);
        k_tokfin<<<32, 256, 0, stream>>>(Y, norm, Wfx, bfx, tok);
        k_kv<<<4, 256, 0, stream>>>(tok, Wk, Wv, kn, vb);
        k_attn<<<32, 256, 0, stream>>>(tok, Wq, kn, vb, attn_scale, srs, ot);
        k_mt<<<dim3(4, 8, 4), 256, 0, stream>>>(ot, Wout, MTb);
        k_gemm2<<<1024, 256, 0, stream>>>(wbuf, MTb, bout, out);
    }
}